// Round 5
// baseline (226.957 us; speedup 1.0000x reference)
//
#include <hip/hip_runtime.h>
#include <hip/hip_bf16.h>
#include <hip/hip_cooperative_groups.h>

namespace cg = cooperative_groups;

#define EPS 1e-5f
#define NSf 65536.0f

typedef unsigned short u16;
typedef __attribute__((ext_vector_type(8))) unsigned short u16x8;
typedef __attribute__((ext_vector_type(4))) unsigned short u16x4;
typedef __attribute__((ext_vector_type(8))) short bf16x8;
typedef __attribute__((ext_vector_type(4))) float f32x4;

// ---------------- workspace layout (float offsets) ----------------
#define WS_Y2T   0                         // 8,388,608 bf16 = 4,194,304 floats (x2t)
#define WS_W3BF  4194304                   // 131072 bf16
#define WS_W2BF  4259840                   // 8192 bf16
#define WS_G1P   4263936                   // 256 * 5120 f32 x1-gram partials
#define WS_G1    5574656                   // 5120 (rows 0..63 = G1, row 64 = cs1)
#define WS_SP    5579776                   // 64 * 12 src-moment partials
#define WS_EFF1  5580544                   // 256
#define WS_SC2   5580800                   // 256
#define WS_SUMP  5581056                   // 16*8*1024 conv3 sum partials
#define WS_SQP   5712128                   // 16*8*1024 sq partials
#define WS_MAXP  5843200                   // 16*8*1024 max partials
#define WS_POOL  5974272                   // 8192
#define WS_FC1   5982464                   // 4096
#define WS_FC2   5986560                   // 2048
#define WS_ROT   5988608                   // 96
#define WS_TRANS 5988704                   // 32
#define WS_DIST  5988736                   // 96   <- cleared in k_prep
#define WS_END   5988832

__device__ __forceinline__ u16 f2b(float f) {
  unsigned u = __float_as_uint(f);
  u += 0x7FFFu + ((u >> 16) & 1);
  return (u16)(u >> 16);
}
__device__ __forceinline__ float b2f(u16 h) { return __uint_as_float(((unsigned)h) << 16); }

__device__ __forceinline__ void gl16(const void* g, void* l) {
  __builtin_amdgcn_global_load_lds((const __attribute__((address_space(1))) unsigned*)g,
                                   (__attribute__((address_space(3))) unsigned*)l, 16, 0, 0);
}

// ---------------- K0: prep = wcast (544 blocks) + src moments (64) + DIST clear
__global__ void k_prep(const float* __restrict__ w3, const float* __restrict__ w2,
                       const float* __restrict__ src, u16* __restrict__ w3bf,
                       u16* __restrict__ w2bf, float* __restrict__ SP,
                       float* __restrict__ DIST) {
  int bid = blockIdx.x, t = threadIdx.x;
  if (bid < 544) {
    int id = bid * 256 + t;
    if (id < 131072) w3bf[id] = f2b(w3[id]);
    else w2bf[id - 131072] = f2b(w2[id - 131072]);
    return;
  }
  int sb = bid - 544;  // 0..63
  if (sb == 0 && t < 96) DIST[t] = 0.f;
  float p[9] = {0, 0, 0, 0, 0, 0, 0, 0, 0};
  for (int it = 0; it < 4; ++it) {
    int id = sb * 1024 + it * 256 + t;
    int b = id >> 13, n = id & 8191;
    float s0 = src[(b * 3 + 0) * 8192 + n];
    float s1 = src[(b * 3 + 1) * 8192 + n];
    float s2 = src[(b * 3 + 2) * 8192 + n];
    p[0] += s0; p[1] += s1; p[2] += s2;
    p[3] = fmaf(s0, s0, p[3]); p[4] = fmaf(s0, s1, p[4]); p[5] = fmaf(s0, s2, p[5]);
    p[6] = fmaf(s1, s1, p[6]); p[7] = fmaf(s1, s2, p[7]); p[8] = fmaf(s2, s2, p[8]);
  }
#pragma unroll
  for (int i = 0; i < 9; ++i)
    for (int off = 32; off; off >>= 1) p[i] += __shfl_xor(p[i], off);
  __shared__ float red[4][9];
  int wv = t >> 6;
  if ((t & 63) == 0) {
#pragma unroll
    for (int i = 0; i < 9; ++i) red[wv][i] = p[i];
  }
  __syncthreads();
  if (t < 9) SP[sb * 12 + t] = red[0][t] + red[1][t] + red[2][t] + red[3][t];
}

// ---------------- K1: finalize layer-1 BN -> effective conv1 weights ----------
__global__ void k_fin1(const float* __restrict__ SP, const float* __restrict__ w1,
                       const float* __restrict__ b1, const float* __restrict__ g1,
                       const float* __restrict__ be1, float* __restrict__ eff) {
  __shared__ float M[9];
  int c = threadIdx.x;  // 64
  if (c < 9) {
    float s = 0.f;
    for (int b = 0; b < 64; ++b) s += SP[b * 12 + c];
    M[c] = s;
  }
  __syncthreads();
  float s0 = M[0], s1 = M[1], s2 = M[2];
  float ss00 = M[3], ss01 = M[4], ss02 = M[5], ss11 = M[6], ss12 = M[7], ss22 = M[8];
  float a0 = w1[c * 3], a1 = w1[c * 3 + 1], a2 = w1[c * 3 + 2], bb = b1[c];
  float dotS = a0 * s0 + a1 * s1 + a2 * s2;
  float sumY = dotS + NSf * bb;
  float sumY2 = a0 * a0 * ss00 + a1 * a1 * ss11 + a2 * a2 * ss22
              + 2.f * (a0 * a1 * ss01 + a0 * a2 * ss02 + a1 * a2 * ss12)
              + 2.f * bb * dotS + NSf * bb * bb;
  float m = sumY / NSf;
  float v = sumY2 / NSf - m * m;
  float sc = g1[c] * rsqrtf(v + EPS);
  float sh = be1[c] - m * sc;
  eff[c * 3 + 0] = sc * a0;
  eff[c * 3 + 1] = sc * a1;
  eff[c * 3 + 2] = sc * a2;
  eff[192 + c] = sc * bb + sh;
}

// ---------------- K2: x1 Gram G1e (80x64, row 64 = colsum) via MFMA ----------
__global__ __launch_bounds__(256) void k_x1stats(const float* __restrict__ src,
                                                 const float* __restrict__ eff,
                                                 float* __restrict__ G1P) {
  __shared__ char T[80 * 512];  // [row 0..79][256 p] bf16, swizzled (40KB)
  int t = threadIdx.x, bid = blockIdx.x;
  int lane = t & 63, lr = lane & 15, lk = lane >> 4;
  int w = __builtin_amdgcn_readfirstlane(t >> 6);
  int P = bid * 256 + t, b = P >> 13, n = P & 8191;
  float s0 = src[(b * 3 + 0) * 8192 + n];
  float s1 = src[(b * 3 + 1) * 8192 + n];
  float s2 = src[(b * 3 + 2) * 8192 + n];
#pragma unroll
  for (int c = 0; c < 64; ++c) {
    float v = fmaxf(fmaf(eff[c * 3], s0, fmaf(eff[c * 3 + 1], s1,
                    fmaf(eff[c * 3 + 2], s2, eff[192 + c]))), 0.f);
    *(u16*)(T + ((c << 9) | ((2 * t) ^ ((c & 7) << 4)))) = f2b(v);
  }
#pragma unroll
  for (int j = 0; j < 16; ++j) {
    int e = j * 256 + t;
    int row = 64 + (e >> 8), p = e & 255;
    *(u16*)(T + ((row << 9) | ((2 * p) ^ ((row & 7) << 4)))) = (row == 64) ? 0x3F80 : 0;
  }
  __syncthreads();
  f32x4 acc[5];
#pragma unroll
  for (int ri = 0; ri < 5; ++ri) acc[ri] = (f32x4){0.f, 0.f, 0.f, 0.f};
  int rb = w * 16 + lr;
#pragma unroll
  for (int ks = 0; ks < 8; ++ks) {
    bf16x8 bb = *(const bf16x8*)(T + ((rb << 9) | ((ks * 64 + lk * 16) ^ ((rb & 7) << 4))));
#pragma unroll
    for (int ri = 0; ri < 5; ++ri) {
      int ra = ri * 16 + lr;
      bf16x8 a = *(const bf16x8*)(T + ((ra << 9) | ((ks * 64 + lk * 16) ^ ((ra & 7) << 4))));
      acc[ri] = __builtin_amdgcn_mfma_f32_16x16x32_bf16(a, bb, acc[ri], 0, 0, 0);
    }
  }
  float* dst = G1P + bid * 5120;
#pragma unroll
  for (int ri = 0; ri < 5; ++ri)
#pragma unroll
    for (int r = 0; r < 4; ++r)
      dst[(ri * 16 + lk * 4 + r) * 64 + w * 16 + lr] = acc[ri][r];
}

// ---------------- K3: reduce G1 partials ----------------
__global__ void k_gred1(const float* __restrict__ G1P, float* __restrict__ G1) {
  int e = blockIdx.x * 256 + threadIdx.x;  // 20 blocks
  float s = 0.f;
  for (int p = 0; p < 256; ++p) s += G1P[p * 5120 + e];
  G1[e] = s;
}

// ---------------- K4: BN2 scale/shift from G1e ----------------
__global__ void k_fin2(const float* __restrict__ G1, const float* __restrict__ w2,
                       const float* __restrict__ b2, const float* __restrict__ g2,
                       const float* __restrict__ be2, float* __restrict__ SC2) {
  int o = blockIdx.x, l = threadIdx.x;  // 128 blocks x 64
  __shared__ float wv[64];
  wv[l] = w2[o * 64 + l];
  __syncthreads();
  float h = 0.f;
  const float* gr = G1 + l * 64;
  for (int k = 0; k < 64; ++k) h = fmaf(gr[k], wv[k], h);
  float q = wv[l] * h;
  float dw = wv[l] * G1[4096 + l];  // cs1 row
  for (int off = 32; off; off >>= 1) { q += __shfl_xor(q, off); dw += __shfl_xor(dw, off); }
  if (l == 0) {
    float bb = b2[o];
    float sumY = dw + NSf * bb;
    float sumY2 = q + 2.f * bb * dw + NSf * bb * bb;
    float m = sumY / NSf;
    float v = sumY2 / NSf - m * m;
    float sc = g2[o] * rsqrtf(v + EPS);
    float sh = be2[o] - m * sc;
    SC2[o] = sc;
    SC2[128 + o] = sc * bb + sh;  // fold conv bias into shift
  }
}

// ---------------- K5: conv2 MFMA + BN2 + ReLU -> x2t bf16 ----------------
__global__ __launch_bounds__(256) void k_conv2(const float* __restrict__ src,
                                               const float* __restrict__ eff,
                                               const u16* __restrict__ w2bf,
                                               const float* __restrict__ SC2,
                                               u16* __restrict__ y2t) {
  __shared__ char WT[16384];  // W2 [128o][64c] bf16 swizzled
  __shared__ char XT[32768];  // x1 [256p][64c] bf16 swizzled
  int t = threadIdx.x, bid = blockIdx.x;
  int lane = t & 63, lr = lane & 15, lk = lane >> 4;
  int w = __builtin_amdgcn_readfirstlane(t >> 6);
#pragma unroll
  for (int i = 0; i < 4; ++i) {
    int s = i * 4096 + t * 16;
    int o = s >> 7, cb = s & 127;
    gl16((const char*)w2bf + ((o << 7) | (cb ^ ((o & 7) << 4))), WT + s);
  }
  int P = bid * 256 + t, b = P >> 13, n = P & 8191;
  float s0 = src[(b * 3 + 0) * 8192 + n];
  float s1 = src[(b * 3 + 1) * 8192 + n];
  float s2 = src[(b * 3 + 2) * 8192 + n];
#pragma unroll
  for (int i = 0; i < 8; ++i) {
    u16x8 pk;
#pragma unroll
    for (int e = 0; e < 8; ++e) {
      int c = i * 8 + e;
      pk[e] = f2b(fmaxf(fmaf(eff[c * 3], s0, fmaf(eff[c * 3 + 1], s1,
                        fmaf(eff[c * 3 + 2], s2, eff[192 + c]))), 0.f));
    }
    *(u16x8*)(XT + ((t << 7) | ((i * 16) ^ ((t & 7) << 4)))) = pk;
  }
  __syncthreads();
  int o0w = (w & 1) * 64, p0w = (w >> 1) * 128;
  f32x4 acc[4][8];
#pragma unroll
  for (int i = 0; i < 4; ++i)
#pragma unroll
    for (int j = 0; j < 8; ++j) acc[i][j] = (f32x4){0.f, 0.f, 0.f, 0.f};
#pragma unroll
  for (int kk = 0; kk < 2; ++kk) {
    bf16x8 a[4], bb[8];
#pragma unroll
    for (int i = 0; i < 4; ++i) {
      int row = o0w + i * 16 + lr;
      a[i] = *(const bf16x8*)(WT + ((row << 7) | ((kk * 64 + lk * 16) ^ ((row & 7) << 4))));
    }
#pragma unroll
    for (int j = 0; j < 8; ++j) {
      int prow = p0w + j * 16 + lr;
      bb[j] = *(const bf16x8*)(XT + ((prow << 7) | ((kk * 64 + lk * 16) ^ ((prow & 7) << 4))));
    }
#pragma unroll
    for (int i = 0; i < 4; ++i)
#pragma unroll
      for (int j = 0; j < 8; ++j)
        acc[i][j] = __builtin_amdgcn_mfma_f32_16x16x32_bf16(a[i], bb[j], acc[i][j], 0, 0, 0);
  }
#pragma unroll
  for (int i = 0; i < 4; ++i) {
    int obch = o0w + i * 16 + lk * 4;
    float4 sc4 = *(const float4*)&SC2[obch];
    float4 sh4 = *(const float4*)&SC2[128 + obch];
#pragma unroll
    for (int j = 0; j < 8; ++j) {
      int p = p0w + j * 16 + lr;
      u16x4 pk;
      pk[0] = f2b(fmaxf(fmaf(sc4.x, acc[i][j][0], sh4.x), 0.f));
      pk[1] = f2b(fmaxf(fmaf(sc4.y, acc[i][j][1], sh4.y), 0.f));
      pk[2] = f2b(fmaxf(fmaf(sc4.z, acc[i][j][2], sh4.z), 0.f));
      pk[3] = f2b(fmaxf(fmaf(sc4.w, acc[i][j][3], sh4.w), 0.f));
      *(u16x4*)(y2t + (size_t)(bid * 256 + p) * 128 + obch) = pk;
    }
  }
}

// ---------------- K6: conv3 — W in regs, X streamed, stats+max in epilogue ---
__device__ __forceinline__ void stage_x(const u16* __restrict__ xit, char* dst, int t) {
#pragma unroll
  for (int q = 0; q < 4; ++q) {
    int s = q * 4096 + t * 16;
    int row = s >> 8, colb = s & 255;
    gl16((const char*)xit + row * 256 + (colb ^ ((row & 7) << 4)), dst + s);
  }
}

__global__ __launch_bounds__(256, 2) void k_conv3(const u16* __restrict__ x2t,
                                                  const u16* __restrict__ w3bf,
                                                  float* __restrict__ SUMP,
                                                  float* __restrict__ SQP,
                                                  float* __restrict__ MAXP) {
  __shared__ char XS[32768];  // 2 x 16KB X tiles [64n][128k], swizzled
  int t = threadIdx.x, lane = t & 63;
  int l15 = lane & 15, l4 = lane >> 4;
  int w = __builtin_amdgcn_readfirstlane(t >> 6);
  int D = blockIdx.x;                      // 512
  // XCD-chunked remap: XCD x = D%8 owns L in [x*64,(x+1)*64) -> the 4 ob-siblings
  // of each (b,nc) group land on ONE XCD; X tile + full W fit its 4MB L2.
  int L = ((D & 7) << 6) | (D >> 3);
  int ob = L & 3, b = (L >> 2) & 7, nc = L >> 5;
  int o0 = ob * 256 + w * 64;
  const u16* xbase = x2t + ((size_t)(b * 8192 + nc * 512)) * 128;
  // W fragments: wave-owned o64, 16 x bf16x8, loaded once
  bf16x8 af[16];
#pragma unroll
  for (int i = 0; i < 4; ++i)
#pragma unroll
    for (int kk = 0; kk < 4; ++kk)
      af[i * 4 + kk] = *(const bf16x8*)((const char*)w3bf +
          (size_t)(o0 + i * 16 + l15) * 256 + kk * 64 + l4 * 16);
  const f32x4 Z = (f32x4){0.f, 0.f, 0.f, 0.f};
  f32x4 acc[4][4];
  float rmax[4][4], rsum[4][4], rsq[4][4];
#pragma unroll
  for (int i = 0; i < 4; ++i)
#pragma unroll
    for (int j = 0; j < 4; ++j) {
      rmax[i][j] = -1e30f; rsum[i][j] = 0.f; rsq[i][j] = 0.f;
    }
  stage_x(xbase, XS, t);
  __syncthreads();
  for (int it = 0; it < 8; ++it) {
    if (it < 7) stage_x(xbase + (size_t)(it + 1) * 8192, XS + ((it + 1) & 1) * 16384, t);
    const char* xb = XS + (it & 1) * 16384;
#pragma unroll
    for (int kk = 0; kk < 4; ++kk) {
      bf16x8 bf[4];
#pragma unroll
      for (int j = 0; j < 4; ++j) {
        int row = j * 16 + l15;
        bf[j] = *(const bf16x8*)(xb + row * 256 + ((kk * 64 + (l4 << 4)) ^ ((lane & 7) << 4)));
      }
#pragma unroll
      for (int i = 0; i < 4; ++i)
#pragma unroll
        for (int j = 0; j < 4; ++j)
          acc[i][j] = __builtin_amdgcn_mfma_f32_16x16x32_bf16(
              af[i * 4 + kk], bf[j], (kk == 0) ? Z : acc[i][j], 0, 0, 0);
    }
    // fold this n64 tile into running sum/sq/max (no acc reset needed: kk==0 uses Z)
#pragma unroll
    for (int i = 0; i < 4; ++i)
#pragma unroll
      for (int r = 0; r < 4; ++r) {
        float v0 = acc[i][0][r], v1 = acc[i][1][r], v2 = acc[i][2][r], v3 = acc[i][3][r];
        rmax[i][r] = fmaxf(rmax[i][r], fmaxf(fmaxf(v0, v1), fmaxf(v2, v3)));
        rsum[i][r] += (v0 + v1) + (v2 + v3);
        float q01 = fmaf(v0, v0, v1 * v1);
        float q23 = fmaf(v2, v2, v3 * v3);
        rsq[i][r] += q01 + q23;
      }
    __syncthreads();
  }
  // reduce across the 16 n-lanes, one writer per o (no atomics anywhere)
#pragma unroll
  for (int i = 0; i < 4; ++i)
#pragma unroll
    for (int r = 0; r < 4; ++r) {
      float mx = rmax[i][r], s = rsum[i][r], q = rsq[i][r];
#pragma unroll
      for (int off = 1; off <= 8; off <<= 1) {
        mx = fmaxf(mx, __shfl_xor(mx, off));
        s += __shfl_xor(s, off);
        q += __shfl_xor(q, off);
      }
      if (l15 == 0) {
        int o = o0 + i * 16 + l4 * 4 + r;
        int sl = (nc * 8 + b) * 1024 + o;
        SUMP[sl] = s; SQP[sl] = q; MAXP[sl] = mx;
      }
    }
}

// ---------------- K7: cooperative tail: pool -> fc1 -> fc2 -> rot -> transform -> loss
__global__ __launch_bounds__(256) void k_tail(
    const float* __restrict__ SUMP, const float* __restrict__ SQP,
    const float* __restrict__ MAXP, const float* __restrict__ b3,
    const float* __restrict__ g3, const float* __restrict__ be3,
    const float* __restrict__ fw1, const float* __restrict__ fb1,
    const float* __restrict__ g4, const float* __restrict__ be4,
    const float* __restrict__ fw2, const float* __restrict__ fb2,
    const float* __restrict__ g5, const float* __restrict__ be5,
    const float* __restrict__ wr, const float* __restrict__ br,
    const float* __restrict__ wt, const float* __restrict__ bt,
    const float* __restrict__ src, const float* __restrict__ tgt,
    float* __restrict__ POOL, float* __restrict__ FC1, float* __restrict__ FC2,
    float* __restrict__ ROT, float* __restrict__ TRANS, float* __restrict__ DIST,
    float* __restrict__ out) {
  cg::grid_group gg = cg::this_grid();
  int bid = blockIdx.x, t = threadIdx.x;  // 256 x 256

  // ---- P0: pool = relu(bn3(max)) ----
  {
    int idx = bid * 256 + t;
    if (idx < 8192) {
      int b = idx >> 10, o = idx & 1023;
      float s = 0.f, q = 0.f;
      for (int p = 0; p < 128; ++p) { s += SUMP[p * 1024 + o]; q += SQP[p * 1024 + o]; }
      float mx = -1e30f;
      for (int ncn = 0; ncn < 16; ++ncn) mx = fmaxf(mx, MAXP[(ncn * 8 + b) * 1024 + o]);
      float bb = b3[o];
      float sumY = s + NSf * bb;
      float sumY2 = q + 2.f * bb * s + NSf * bb * bb;
      float m = sumY / NSf;
      float v = sumY2 / NSf - m * m;
      float sc = g3[o] * rsqrtf(v + EPS);
      float sh = be3[o] - m * sc;
      POOL[idx] = fmaxf(fmaf(sc, mx + bb, sh), 0.f);
    }
  }
  gg.sync();
  // ---- P1: fc1 (512 out, K=1024) ----
  {
    int ol = t >> 7, b = (t >> 4) & 7, ks = t & 15;
    int o = bid * 2 + ol;
    const float4* wrow = (const float4*)(fw1 + (size_t)o * 1024 + ks * 64);
    const float4* xrow = (const float4*)(POOL + b * 1024 + ks * 64);
    float acc = 0.f;
#pragma unroll
    for (int j = 0; j < 16; ++j) {
      float4 w4 = wrow[j], x4 = xrow[j];
      acc += w4.x * x4.x + w4.y * x4.y + w4.z * x4.z + w4.w * x4.w;
    }
    acc += __shfl_xor(acc, 1); acc += __shfl_xor(acc, 2);
    acc += __shfl_xor(acc, 4); acc += __shfl_xor(acc, 8);
    __shared__ float yt1[2][8];
    __shared__ float ss1[2][2];
    if (ks == 0) yt1[ol][b] = acc + fb1[o];
    __syncthreads();
    if (t < 2) {
      float m = 0.f;
      for (int i = 0; i < 8; ++i) m += yt1[t][i];
      m *= 0.125f;
      float v = 0.f;
      for (int i = 0; i < 8; ++i) { float d = yt1[t][i] - m; v = fmaf(d, d, v); }
      v *= 0.125f;
      float sc = g4[bid * 2 + t] * rsqrtf(v + EPS);
      ss1[t][0] = sc; ss1[t][1] = be4[bid * 2 + t] - m * sc;
    }
    __syncthreads();
    if (ks == 0) FC1[b * 512 + o] = fmaxf(fmaf(ss1[ol][0], yt1[ol][b], ss1[ol][1]), 0.f);
  }
  gg.sync();
  // ---- P2: fc2 (256 out, K=512) ----
  {
    int b = t >> 5, ks = t & 31;
    int o = bid;
    const float4* wrow = (const float4*)(fw2 + (size_t)o * 512 + ks * 16);
    const float4* xrow = (const float4*)(FC1 + b * 512 + ks * 16);
    float acc = 0.f;
#pragma unroll
    for (int j = 0; j < 4; ++j) {
      float4 w4 = wrow[j], x4 = xrow[j];
      acc += w4.x * x4.x + w4.y * x4.y + w4.z * x4.z + w4.w * x4.w;
    }
    acc += __shfl_xor(acc, 1); acc += __shfl_xor(acc, 2);
    acc += __shfl_xor(acc, 4); acc += __shfl_xor(acc, 8);
    acc += __shfl_xor(acc, 16);
    __shared__ float yt2[8];
    __shared__ float ss2[2];
    if (ks == 0) yt2[b] = acc + fb2[o];
    __syncthreads();
    if (t == 0) {
      float m = 0.f;
      for (int i = 0; i < 8; ++i) m += yt2[i];
      m *= 0.125f;
      float v = 0.f;
      for (int i = 0; i < 8; ++i) { float d = yt2[i] - m; v = fmaf(d, d, v); }
      v *= 0.125f;
      float sc = g5[o] * rsqrtf(v + EPS);
      ss2[0] = sc; ss2[1] = be5[o] - m * sc;
    }
    __syncthreads();
    if (ks == 0) FC2[b * 256 + o] = fmaxf(fmaf(ss2[0], yt2[b], ss2[1]), 0.f);
  }
  gg.sync();
  // ---- P3: rot/trans heads (96 blocks busy) ----
  {
    if (bid < 96 && t < 64) {
      int b = bid / 12, j = bid % 12;
      float p = 0.f;
#pragma unroll
      for (int i = 0; i < 4; ++i) {
        int kk = i * 64 + t;
        float w = (j < 9) ? wr[j * 256 + kk] : wt[(j - 9) * 256 + kk];
        p = fmaf(w, FC2[b * 256 + kk], p);
      }
      for (int off = 32; off; off >>= 1) p += __shfl_xor(p, off);
      if (t == 0) {
        if (j < 9)
          ROT[b * 9 + j] = p + br[j] + ((j == 0 || j == 4 || j == 8) ? 1.f : 0.f);
        else
          TRANS[b * 3 + (j - 9)] = p + bt[j - 9];
      }
    }
  }
  gg.sync();
  // ---- P4: apply transform + dist partials ----
  {
    int P = bid * 256 + t;
    int b = P >> 13, n = P & 8191;
    float s0 = src[(b * 3 + 0) * 8192 + n];
    float s1 = src[(b * 3 + 1) * 8192 + n];
    float s2 = src[(b * 3 + 2) * 8192 + n];
    const float* R = ROT + b * 9;
    const float* T = TRANS + b * 3;
    float st[3];
#pragma unroll
    for (int c = 0; c < 3; ++c) {
      st[c] = fmaf(s0, R[0 * 3 + c], fmaf(s1, R[1 * 3 + c], fmaf(s2, R[2 * 3 + c], T[c])));
      out[1 + (b * 3 + c) * 8192 + n] = st[c];
    }
    float tg[3];
#pragma unroll
    for (int i = 0; i < 3; ++i) tg[i] = tgt[(b * 3 + i) * 8192 + n];
    float d[9];
#pragma unroll
    for (int i = 0; i < 3; ++i)
#pragma unroll
      for (int j = 0; j < 3; ++j) {
        float df = st[j] - tg[i];
        d[i * 3 + j] = df * df;
      }
#pragma unroll
    for (int k = 0; k < 9; ++k)
      for (int off = 32; off; off >>= 1) d[k] += __shfl_xor(d[k], off);
    __shared__ float red4[4][9];
    int wv = t >> 6;
    if ((t & 63) == 0) {
#pragma unroll
      for (int k = 0; k < 9; ++k) red4[wv][k] = d[k];
    }
    __syncthreads();
    if (t < 9) {
      float s = red4[0][t] + red4[1][t] + red4[2][t] + red4[3][t];
      atomicAdd(&DIST[b * 9 + t], s);
    }
  }
  gg.sync();
  // ---- P5: loss ----
  if (bid == 0 && t == 0) {
    float acc = 0.f;
    for (int b = 0; b < 8; ++b) {
      const float* Dd = DIST + b * 9;
      for (int j = 0; j < 3; ++j)
        acc += fminf(Dd[j], fminf(Dd[3 + j], Dd[6 + j]));
      for (int i = 0; i < 3; ++i)
        acc += fminf(Dd[i * 3], fminf(Dd[i * 3 + 1], Dd[i * 3 + 2]));
    }
    out[0] = acc / 24.f;
  }
}

extern "C" void kernel_launch(void* const* d_in, const int* in_sizes, int n_in,
                              void* d_out, int out_size, void* d_ws, size_t ws_size,
                              hipStream_t stream) {
  const float* src = (const float*)d_in[0];
  const float* tgt = (const float*)d_in[1];
  const float* w1 = (const float*)d_in[2];
  const float* b1 = (const float*)d_in[3];
  const float* w2 = (const float*)d_in[4];
  const float* b2 = (const float*)d_in[5];
  const float* w3 = (const float*)d_in[6];
  const float* b3 = (const float*)d_in[7];
  const float* fw1 = (const float*)d_in[8];
  const float* fb1 = (const float*)d_in[9];
  const float* fw2 = (const float*)d_in[10];
  const float* fb2 = (const float*)d_in[11];
  const float* wr = (const float*)d_in[12];
  const float* br = (const float*)d_in[13];
  const float* wt = (const float*)d_in[14];
  const float* bt = (const float*)d_in[15];
  const float* g1 = (const float*)d_in[16];
  const float* be1 = (const float*)d_in[17];
  const float* g2 = (const float*)d_in[18];
  const float* be2 = (const float*)d_in[19];
  const float* g3 = (const float*)d_in[20];
  const float* be3 = (const float*)d_in[21];
  const float* g4 = (const float*)d_in[22];
  const float* be4 = (const float*)d_in[23];
  const float* g5 = (const float*)d_in[24];
  const float* be5 = (const float*)d_in[25];
  float* out = (float*)d_out;
  float* ws = (float*)d_ws;
  u16* y2t = (u16*)(ws + WS_Y2T);
  u16* w3bf = (u16*)(ws + WS_W3BF);
  u16* w2bf = (u16*)(ws + WS_W2BF);

  k_prep<<<608, 256, 0, stream>>>(w3, w2, src, w3bf, w2bf, ws + WS_SP, ws + WS_DIST);
  k_fin1<<<1, 64, 0, stream>>>(ws + WS_SP, w1, b1, g1, be1, ws + WS_EFF1);
  k_x1stats<<<256, 256, 0, stream>>>(src, ws + WS_EFF1, ws + WS_G1P);
  k_gred1<<<20, 256, 0, stream>>>(ws + WS_G1P, ws + WS_G1);
  k_fin2<<<128, 64, 0, stream>>>(ws + WS_G1, w2, b2, g2, be2, ws + WS_SC2);
  k_conv2<<<256, 256, 0, stream>>>(src, ws + WS_EFF1, w2bf, ws + WS_SC2, y2t);
  k_conv3<<<512, 256, 0, stream>>>(y2t, w3bf, ws + WS_SUMP, ws + WS_SQP, ws + WS_MAXP);

  const float* SUMPp = ws + WS_SUMP;
  const float* SQPp = ws + WS_SQP;
  const float* MAXPp = ws + WS_MAXP;
  float* POOLp = ws + WS_POOL;
  float* FC1p = ws + WS_FC1;
  float* FC2p = ws + WS_FC2;
  float* ROTp = ws + WS_ROT;
  float* TRANSp = ws + WS_TRANS;
  float* DISTp = ws + WS_DIST;
  void* kargs[] = {
      (void*)&SUMPp, (void*)&SQPp, (void*)&MAXPp, (void*)&b3, (void*)&g3, (void*)&be3,
      (void*)&fw1, (void*)&fb1, (void*)&g4, (void*)&be4,
      (void*)&fw2, (void*)&fb2, (void*)&g5, (void*)&be5,
      (void*)&wr, (void*)&br, (void*)&wt, (void*)&bt,
      (void*)&src, (void*)&tgt,
      (void*)&POOLp, (void*)&FC1p, (void*)&FC2p, (void*)&ROTp, (void*)&TRANSp,
      (void*)&DISTp, (void*)&out};
  hipLaunchCooperativeKernel((const void*)k_tail, dim3(256), dim3(256), kargs, 0, stream);
}

// Round 6
// 103.055 us; speedup vs baseline: 2.2023x; 2.2023x over previous
//
#include <hip/hip_runtime.h>
#include <hip/hip_bf16.h>

#define EPS 1e-5f
#define NSf 65536.0f

typedef unsigned short u16;
typedef __attribute__((ext_vector_type(8))) unsigned short u16x8;
typedef __attribute__((ext_vector_type(4))) unsigned short u16x4;
typedef __attribute__((ext_vector_type(8))) short bf16x8;
typedef __attribute__((ext_vector_type(4))) float f32x4;

// ---------------- workspace layout (float offsets) ----------------
#define WS_Y2T   0                         // 8,388,608 bf16 = 4,194,304 floats (x2t)
#define WS_W3BF  4194304                   // 131072 bf16
#define WS_W2BF  4259840                   // 8192 bf16
#define WS_G1P   4263936                   // 256 * 5120 f32 x1-gram partials
#define WS_G1    5574656                   // 5120 (rows 0..63 = G1, row 64 = cs1)
#define WS_SP    5579776                   // 64 * 12 src-moment partials
#define WS_EFF1  5580544                   // 256
#define WS_SC2   5580800                   // 256
#define WS_SUMP  5581056                   // 16*8*1024 conv3 sum partials
#define WS_SQP   5712128                   // 16*8*1024 sq partials
#define WS_MAXP  5843200                   // 16*8*1024 max partials
#define WS_POOL  5974272                   // 8192
#define WS_FC1   5982464                   // 4096
#define WS_FC2   5986560                   // 2048
#define WS_DIST  5988608                   // 96 + counter  <- cleared in k_prep
#define WS_CNT   5988704                   // 1
#define WS_END   5988708

__device__ __forceinline__ u16 f2b(float f) {
  unsigned u = __float_as_uint(f);
  u += 0x7FFFu + ((u >> 16) & 1);
  return (u16)(u >> 16);
}
__device__ __forceinline__ float b2f(u16 h) { return __uint_as_float(((unsigned)h) << 16); }

__device__ __forceinline__ void gl16(const void* g, void* l) {
  __builtin_amdgcn_global_load_lds((const __attribute__((address_space(1))) unsigned*)g,
                                   (__attribute__((address_space(3))) unsigned*)l, 16, 0, 0);
}

// ---------------- K0: prep = wcast (544 blocks) + src moments (64) + clears --
__global__ void k_prep(const float* __restrict__ w3, const float* __restrict__ w2,
                       const float* __restrict__ src, u16* __restrict__ w3bf,
                       u16* __restrict__ w2bf, float* __restrict__ SP,
                       float* __restrict__ DIST) {
  int bid = blockIdx.x, t = threadIdx.x;
  if (bid < 544) {
    int id = bid * 256 + t;
    if (id < 131072) w3bf[id] = f2b(w3[id]);
    else w2bf[id - 131072] = f2b(w2[id - 131072]);
    return;
  }
  int sb = bid - 544;  // 0..63
  if (sb == 0 && t < 100) DIST[t] = 0.f;  // DIST[96] + CNT
  float p[9] = {0, 0, 0, 0, 0, 0, 0, 0, 0};
  for (int it = 0; it < 4; ++it) {
    int id = sb * 1024 + it * 256 + t;
    int b = id >> 13, n = id & 8191;
    float s0 = src[(b * 3 + 0) * 8192 + n];
    float s1 = src[(b * 3 + 1) * 8192 + n];
    float s2 = src[(b * 3 + 2) * 8192 + n];
    p[0] += s0; p[1] += s1; p[2] += s2;
    p[3] = fmaf(s0, s0, p[3]); p[4] = fmaf(s0, s1, p[4]); p[5] = fmaf(s0, s2, p[5]);
    p[6] = fmaf(s1, s1, p[6]); p[7] = fmaf(s1, s2, p[7]); p[8] = fmaf(s2, s2, p[8]);
  }
#pragma unroll
  for (int i = 0; i < 9; ++i)
    for (int off = 32; off; off >>= 1) p[i] += __shfl_xor(p[i], off);
  __shared__ float red[4][9];
  int wv = t >> 6;
  if ((t & 63) == 0) {
#pragma unroll
    for (int i = 0; i < 9; ++i) red[wv][i] = p[i];
  }
  __syncthreads();
  if (t < 9) SP[sb * 12 + t] = red[0][t] + red[1][t] + red[2][t] + red[3][t];
}

// ---------------- K1: finalize layer-1 BN -> effective conv1 weights ----------
__global__ void k_fin1(const float* __restrict__ SP, const float* __restrict__ w1,
                       const float* __restrict__ b1, const float* __restrict__ g1,
                       const float* __restrict__ be1, float* __restrict__ eff) {
  __shared__ float M[9];
  int c = threadIdx.x;  // 64
  if (c < 9) {
    float s = 0.f;
    for (int b = 0; b < 64; ++b) s += SP[b * 12 + c];
    M[c] = s;
  }
  __syncthreads();
  float s0 = M[0], s1 = M[1], s2 = M[2];
  float ss00 = M[3], ss01 = M[4], ss02 = M[5], ss11 = M[6], ss12 = M[7], ss22 = M[8];
  float a0 = w1[c * 3], a1 = w1[c * 3 + 1], a2 = w1[c * 3 + 2], bb = b1[c];
  float dotS = a0 * s0 + a1 * s1 + a2 * s2;
  float sumY = dotS + NSf * bb;
  float sumY2 = a0 * a0 * ss00 + a1 * a1 * ss11 + a2 * a2 * ss22
              + 2.f * (a0 * a1 * ss01 + a0 * a2 * ss02 + a1 * a2 * ss12)
              + 2.f * bb * dotS + NSf * bb * bb;
  float m = sumY / NSf;
  float v = sumY2 / NSf - m * m;
  float sc = g1[c] * rsqrtf(v + EPS);
  float sh = be1[c] - m * sc;
  eff[c * 3 + 0] = sc * a0;
  eff[c * 3 + 1] = sc * a1;
  eff[c * 3 + 2] = sc * a2;
  eff[192 + c] = sc * bb + sh;
}

// ---------------- K2: x1 Gram G1e (80x64, row 64 = colsum) via MFMA ----------
__global__ __launch_bounds__(256) void k_x1stats(const float* __restrict__ src,
                                                 const float* __restrict__ eff,
                                                 float* __restrict__ G1P) {
  __shared__ char T[80 * 512];  // [row 0..79][256 p] bf16, swizzled (40KB)
  int t = threadIdx.x, bid = blockIdx.x;
  int lane = t & 63, lr = lane & 15, lk = lane >> 4;
  int w = __builtin_amdgcn_readfirstlane(t >> 6);
  int P = bid * 256 + t, b = P >> 13, n = P & 8191;
  float s0 = src[(b * 3 + 0) * 8192 + n];
  float s1 = src[(b * 3 + 1) * 8192 + n];
  float s2 = src[(b * 3 + 2) * 8192 + n];
#pragma unroll
  for (int c = 0; c < 64; ++c) {
    float v = fmaxf(fmaf(eff[c * 3], s0, fmaf(eff[c * 3 + 1], s1,
                    fmaf(eff[c * 3 + 2], s2, eff[192 + c]))), 0.f);
    *(u16*)(T + ((c << 9) | ((2 * t) ^ ((c & 7) << 4)))) = f2b(v);
  }
#pragma unroll
  for (int j = 0; j < 16; ++j) {
    int e = j * 256 + t;
    int row = 64 + (e >> 8), p = e & 255;
    *(u16*)(T + ((row << 9) | ((2 * p) ^ ((row & 7) << 4)))) = (row == 64) ? 0x3F80 : 0;
  }
  __syncthreads();
  f32x4 acc[5];
#pragma unroll
  for (int ri = 0; ri < 5; ++ri) acc[ri] = (f32x4){0.f, 0.f, 0.f, 0.f};
  int rb = w * 16 + lr;
#pragma unroll
  for (int ks = 0; ks < 8; ++ks) {
    bf16x8 bb = *(const bf16x8*)(T + ((rb << 9) | ((ks * 64 + lk * 16) ^ ((rb & 7) << 4))));
#pragma unroll
    for (int ri = 0; ri < 5; ++ri) {
      int ra = ri * 16 + lr;
      bf16x8 a = *(const bf16x8*)(T + ((ra << 9) | ((ks * 64 + lk * 16) ^ ((ra & 7) << 4))));
      acc[ri] = __builtin_amdgcn_mfma_f32_16x16x32_bf16(a, bb, acc[ri], 0, 0, 0);
    }
  }
  float* dst = G1P + bid * 5120;
#pragma unroll
  for (int ri = 0; ri < 5; ++ri)
#pragma unroll
    for (int r = 0; r < 4; ++r)
      dst[(ri * 16 + lk * 4 + r) * 64 + w * 16 + lr] = acc[ri][r];
}

// ---------------- K3: reduce G1 partials ----------------
__global__ void k_gred1(const float* __restrict__ G1P, float* __restrict__ G1) {
  int e = blockIdx.x * 256 + threadIdx.x;  // 20 blocks
  float s = 0.f;
  for (int p = 0; p < 256; ++p) s += G1P[p * 5120 + e];
  G1[e] = s;
}

// ---------------- K4: BN2 scale/shift from G1e ----------------
__global__ void k_fin2(const float* __restrict__ G1, const float* __restrict__ w2,
                       const float* __restrict__ b2, const float* __restrict__ g2,
                       const float* __restrict__ be2, float* __restrict__ SC2) {
  int o = blockIdx.x, l = threadIdx.x;  // 128 blocks x 64
  __shared__ float wv[64];
  wv[l] = w2[o * 64 + l];
  __syncthreads();
  float h = 0.f;
  const float* gr = G1 + l * 64;
  for (int k = 0; k < 64; ++k) h = fmaf(gr[k], wv[k], h);
  float q = wv[l] * h;
  float dw = wv[l] * G1[4096 + l];  // cs1 row
  for (int off = 32; off; off >>= 1) { q += __shfl_xor(q, off); dw += __shfl_xor(dw, off); }
  if (l == 0) {
    float bb = b2[o];
    float sumY = dw + NSf * bb;
    float sumY2 = q + 2.f * bb * dw + NSf * bb * bb;
    float m = sumY / NSf;
    float v = sumY2 / NSf - m * m;
    float sc = g2[o] * rsqrtf(v + EPS);
    float sh = be2[o] - m * sc;
    SC2[o] = sc;
    SC2[128 + o] = sc * bb + sh;  // fold conv bias into shift
  }
}

// ---------------- K5: conv2 MFMA + BN2 + ReLU -> x2t bf16 ----------------
__global__ __launch_bounds__(256) void k_conv2(const float* __restrict__ src,
                                               const float* __restrict__ eff,
                                               const u16* __restrict__ w2bf,
                                               const float* __restrict__ SC2,
                                               u16* __restrict__ y2t) {
  __shared__ char WT[16384];  // W2 [128o][64c] bf16 swizzled
  __shared__ char XT[32768];  // x1 [256p][64c] bf16 swizzled
  int t = threadIdx.x, bid = blockIdx.x;
  int lane = t & 63, lr = lane & 15, lk = lane >> 4;
  int w = __builtin_amdgcn_readfirstlane(t >> 6);
#pragma unroll
  for (int i = 0; i < 4; ++i) {
    int s = i * 4096 + t * 16;
    int o = s >> 7, cb = s & 127;
    gl16((const char*)w2bf + ((o << 7) | (cb ^ ((o & 7) << 4))), WT + s);
  }
  int P = bid * 256 + t, b = P >> 13, n = P & 8191;
  float s0 = src[(b * 3 + 0) * 8192 + n];
  float s1 = src[(b * 3 + 1) * 8192 + n];
  float s2 = src[(b * 3 + 2) * 8192 + n];
#pragma unroll
  for (int i = 0; i < 8; ++i) {
    u16x8 pk;
#pragma unroll
    for (int e = 0; e < 8; ++e) {
      int c = i * 8 + e;
      pk[e] = f2b(fmaxf(fmaf(eff[c * 3], s0, fmaf(eff[c * 3 + 1], s1,
                        fmaf(eff[c * 3 + 2], s2, eff[192 + c]))), 0.f));
    }
    *(u16x8*)(XT + ((t << 7) | ((i * 16) ^ ((t & 7) << 4)))) = pk;
  }
  __syncthreads();
  int o0w = (w & 1) * 64, p0w = (w >> 1) * 128;
  f32x4 acc[4][8];
#pragma unroll
  for (int i = 0; i < 4; ++i)
#pragma unroll
    for (int j = 0; j < 8; ++j) acc[i][j] = (f32x4){0.f, 0.f, 0.f, 0.f};
#pragma unroll
  for (int kk = 0; kk < 2; ++kk) {
    bf16x8 a[4], bb[8];
#pragma unroll
    for (int i = 0; i < 4; ++i) {
      int row = o0w + i * 16 + lr;
      a[i] = *(const bf16x8*)(WT + ((row << 7) | ((kk * 64 + lk * 16) ^ ((row & 7) << 4))));
    }
#pragma unroll
    for (int j = 0; j < 8; ++j) {
      int prow = p0w + j * 16 + lr;
      bb[j] = *(const bf16x8*)(XT + ((prow << 7) | ((kk * 64 + lk * 16) ^ ((prow & 7) << 4))));
    }
#pragma unroll
    for (int i = 0; i < 4; ++i)
#pragma unroll
      for (int j = 0; j < 8; ++j)
        acc[i][j] = __builtin_amdgcn_mfma_f32_16x16x32_bf16(a[i], bb[j], acc[i][j], 0, 0, 0);
  }
#pragma unroll
  for (int i = 0; i < 4; ++i) {
    int obch = o0w + i * 16 + lk * 4;
    float4 sc4 = *(const float4*)&SC2[obch];
    float4 sh4 = *(const float4*)&SC2[128 + obch];
#pragma unroll
    for (int j = 0; j < 8; ++j) {
      int p = p0w + j * 16 + lr;
      u16x4 pk;
      pk[0] = f2b(fmaxf(fmaf(sc4.x, acc[i][j][0], sh4.x), 0.f));
      pk[1] = f2b(fmaxf(fmaf(sc4.y, acc[i][j][1], sh4.y), 0.f));
      pk[2] = f2b(fmaxf(fmaf(sc4.z, acc[i][j][2], sh4.z), 0.f));
      pk[3] = f2b(fmaxf(fmaf(sc4.w, acc[i][j][3], sh4.w), 0.f));
      *(u16x4*)(y2t + (size_t)(bid * 256 + p) * 128 + obch) = pk;
    }
  }
}

// ---------------- K6: conv3 — W in regs, X streamed, stats+max in epilogue ---
__device__ __forceinline__ void stage_x(const u16* __restrict__ xit, char* dst, int t) {
#pragma unroll
  for (int q = 0; q < 4; ++q) {
    int s = q * 4096 + t * 16;
    int row = s >> 8, colb = s & 255;
    gl16((const char*)xit + row * 256 + (colb ^ ((row & 7) << 4)), dst + s);
  }
}

__global__ __launch_bounds__(256, 2) void k_conv3(const u16* __restrict__ x2t,
                                                  const u16* __restrict__ w3bf,
                                                  float* __restrict__ SUMP,
                                                  float* __restrict__ SQP,
                                                  float* __restrict__ MAXP) {
  __shared__ char XS[32768];  // 2 x 16KB X tiles [64n][128k], swizzled
  int t = threadIdx.x, lane = t & 63;
  int l15 = lane & 15, l4 = lane >> 4;
  int w = __builtin_amdgcn_readfirstlane(t >> 6);
  int D = blockIdx.x;                      // 512
  // XCD-chunked remap: the 4 ob-siblings of each (b,nc) group land on ONE XCD.
  int L = ((D & 7) << 6) | (D >> 3);
  int ob = L & 3, b = (L >> 2) & 7, nc = L >> 5;
  int o0 = ob * 256 + w * 64;
  const u16* xbase = x2t + ((size_t)(b * 8192 + nc * 512)) * 128;
  bf16x8 af[16];
#pragma unroll
  for (int i = 0; i < 4; ++i)
#pragma unroll
    for (int kk = 0; kk < 4; ++kk)
      af[i * 4 + kk] = *(const bf16x8*)((const char*)w3bf +
          (size_t)(o0 + i * 16 + l15) * 256 + kk * 64 + l4 * 16);
  const f32x4 Z = (f32x4){0.f, 0.f, 0.f, 0.f};
  f32x4 acc[4][4];
  float rmax[4][4], rsum[4][4], rsq[4][4];
#pragma unroll
  for (int i = 0; i < 4; ++i)
#pragma unroll
    for (int j = 0; j < 4; ++j) {
      rmax[i][j] = -1e30f; rsum[i][j] = 0.f; rsq[i][j] = 0.f;
    }
  stage_x(xbase, XS, t);
  __syncthreads();
  for (int it = 0; it < 8; ++it) {
    if (it < 7) stage_x(xbase + (size_t)(it + 1) * 8192, XS + ((it + 1) & 1) * 16384, t);
    const char* xb = XS + (it & 1) * 16384;
#pragma unroll
    for (int kk = 0; kk < 4; ++kk) {
      bf16x8 bf[4];
#pragma unroll
      for (int j = 0; j < 4; ++j) {
        int row = j * 16 + l15;
        bf[j] = *(const bf16x8*)(xb + row * 256 + ((kk * 64 + (l4 << 4)) ^ ((lane & 7) << 4)));
      }
#pragma unroll
      for (int i = 0; i < 4; ++i)
#pragma unroll
        for (int j = 0; j < 4; ++j)
          acc[i][j] = __builtin_amdgcn_mfma_f32_16x16x32_bf16(
              af[i * 4 + kk], bf[j], (kk == 0) ? Z : acc[i][j], 0, 0, 0);
    }
#pragma unroll
    for (int i = 0; i < 4; ++i)
#pragma unroll
      for (int r = 0; r < 4; ++r) {
        float v0 = acc[i][0][r], v1 = acc[i][1][r], v2 = acc[i][2][r], v3 = acc[i][3][r];
        rmax[i][r] = fmaxf(rmax[i][r], fmaxf(fmaxf(v0, v1), fmaxf(v2, v3)));
        rsum[i][r] += (v0 + v1) + (v2 + v3);
        float q01 = fmaf(v0, v0, v1 * v1);
        float q23 = fmaf(v2, v2, v3 * v3);
        rsq[i][r] += q01 + q23;
      }
    __syncthreads();
  }
#pragma unroll
  for (int i = 0; i < 4; ++i)
#pragma unroll
    for (int r = 0; r < 4; ++r) {
      float mx = rmax[i][r], s = rsum[i][r], q = rsq[i][r];
#pragma unroll
      for (int off = 1; off <= 8; off <<= 1) {
        mx = fmaxf(mx, __shfl_xor(mx, off));
        s += __shfl_xor(s, off);
        q += __shfl_xor(q, off);
      }
      if (l15 == 0) {
        int o = o0 + i * 16 + l4 * 4 + r;
        int sl = (nc * 8 + b) * 1024 + o;
        SUMP[sl] = s; SQP[sl] = q; MAXP[sl] = mx;
      }
    }
}

// ---------------- K7: reduce partials, finalize BN3 + pool ----------------
__global__ void k_pool(const float* __restrict__ SUMP, const float* __restrict__ SQP,
                       const float* __restrict__ MAXP, const float* __restrict__ b3,
                       const float* __restrict__ g3, const float* __restrict__ be3,
                       float* __restrict__ POOL) {
  int idx = blockIdx.x * 256 + threadIdx.x;  // 8192 = b*1024+o
  int b = idx >> 10, o = idx & 1023;
  float s = 0.f, q = 0.f;
  for (int p = 0; p < 128; ++p) {
    s += SUMP[p * 1024 + o];
    q += SQP[p * 1024 + o];
  }
  float mx = -1e30f;
  for (int ncn = 0; ncn < 16; ++ncn) mx = fmaxf(mx, MAXP[(ncn * 8 + b) * 1024 + o]);
  float bb = b3[o];
  float sumY = s + NSf * bb;
  float sumY2 = q + 2.f * bb * s + NSf * bb * bb;
  float m = sumY / NSf;
  float v = sumY2 / NSf - m * m;
  float sc = g3[o] * rsqrtf(v + EPS);
  float sh = be3[o] - m * sc;
  POOL[idx] = fmaxf(fmaf(sc, mx + bb, sh), 0.f);
}

// ---------------- K8/K9: FC + BN(8) + ReLU ----------------
__global__ void k_fc(const float* __restrict__ xin, const float* __restrict__ w,
                     const float* __restrict__ bias, const float* __restrict__ g,
                     const float* __restrict__ be, float* __restrict__ out,
                     int K, int O) {
  int o = blockIdx.x, lane = threadIdx.x;  // 64 threads
  float yb[8] = {0.f, 0.f, 0.f, 0.f, 0.f, 0.f, 0.f, 0.f};
  for (int j = 0; j < K; j += 64) {
    float wv = w[(size_t)o * K + j + lane];
#pragma unroll
    for (int b = 0; b < 8; ++b) yb[b] = fmaf(wv, xin[b * K + j + lane], yb[b]);
  }
#pragma unroll
  for (int b = 0; b < 8; ++b)
    for (int off = 32; off; off >>= 1) yb[b] += __shfl_xor(yb[b], off);
  if (lane == 0) {
    float y[8];
    float m = 0.f;
#pragma unroll
    for (int b = 0; b < 8; ++b) { y[b] = yb[b] + bias[o]; m += y[b]; }
    m *= 0.125f;
    float v = 0.f;
#pragma unroll
    for (int b = 0; b < 8; ++b) { float d = y[b] - m; v = fmaf(d, d, v); }
    v *= 0.125f;
    float sc = g[o] * rsqrtf(v + EPS);
    float sh = be[o] - m * sc;
#pragma unroll
    for (int b = 0; b < 8; ++b) out[b * O + o] = fmaxf(fmaf(sc, y[b], sh), 0.f);
  }
}

// ---- K10: transform (+redundant per-block rot head, +loss via counter) ------
__global__ __launch_bounds__(256) void k_transform(
    const float* __restrict__ src, const float* __restrict__ tgt,
    const float* __restrict__ FC2, const float* __restrict__ wr,
    const float* __restrict__ br, const float* __restrict__ wt,
    const float* __restrict__ bt, float* __restrict__ out,
    float* __restrict__ DIST, unsigned* __restrict__ CNT) {
  int bx = blockIdx.x, t = threadIdx.x;
  int b = bx >> 5;
  int n = ((bx & 31) << 8) + t;
  int w = t >> 6, lane = t & 63;
  __shared__ float RT[12];
  // rot/trans head, recomputed per block (3K FMA): wave w -> outputs 3w..3w+2
  const float* xf = FC2 + b * 256;
#pragma unroll
  for (int jj = 0; jj < 3; ++jj) {
    int j = w * 3 + jj;  // wave-uniform
    float p = 0.f;
#pragma unroll
    for (int i = 0; i < 4; ++i) {
      int kk = i * 64 + lane;
      float wv = (j < 9) ? wr[j * 256 + kk] : wt[(j - 9) * 256 + kk];
      p = fmaf(wv, xf[kk], p);
    }
    for (int off = 32; off; off >>= 1) p += __shfl_xor(p, off);
    if (lane == 0)
      RT[j] = (j < 9) ? (p + br[j] + ((j == 0 || j == 4 || j == 8) ? 1.f : 0.f))
                      : (p + bt[j - 9]);
  }
  __syncthreads();
  float s0 = src[(b * 3 + 0) * 8192 + n];
  float s1 = src[(b * 3 + 1) * 8192 + n];
  float s2 = src[(b * 3 + 2) * 8192 + n];
  float st[3];
#pragma unroll
  for (int c = 0; c < 3; ++c) {
    st[c] = fmaf(s0, RT[c], fmaf(s1, RT[3 + c], fmaf(s2, RT[6 + c], RT[9 + c])));
    out[1 + (b * 3 + c) * 8192 + n] = st[c];
  }
  float tg[3];
#pragma unroll
  for (int i = 0; i < 3; ++i) tg[i] = tgt[(b * 3 + i) * 8192 + n];
  float d[9];
#pragma unroll
  for (int i = 0; i < 3; ++i)
#pragma unroll
    for (int j = 0; j < 3; ++j) {
      float df = st[j] - tg[i];
      d[i * 3 + j] = df * df;
    }
#pragma unroll
  for (int k = 0; k < 9; ++k)
    for (int off = 32; off; off >>= 1) d[k] += __shfl_xor(d[k], off);
  __shared__ float red4[4][9];
  if ((t & 63) == 0) {
#pragma unroll
    for (int k = 0; k < 9; ++k) red4[w][k] = d[k];
  }
  __syncthreads();
  if (t < 9) {
    float s = red4[0][t] + red4[1][t] + red4[2][t] + red4[3][t];
    atomicAdd(&DIST[b * 9 + t], s);
  }
  // completion counter: barrier drains this block's atomics; last block does loss
  __syncthreads();
  __shared__ unsigned rank;
  if (t == 0) {
    __threadfence();
    rank = atomicAdd(CNT, 1u);
  }
  __syncthreads();
  if (rank == 255u) {
    __shared__ float Dl[72];
    if (t < 72) Dl[t] = atomicAdd(&DIST[t], 0.f);  // atomic load, L2-coherent
    __syncthreads();
    if (t == 0) {
      float acc = 0.f;
      for (int bb = 0; bb < 8; ++bb) {
        const float* D = Dl + bb * 9;
        for (int j = 0; j < 3; ++j)
          acc += fminf(D[j], fminf(D[3 + j], D[6 + j]));
        for (int i = 0; i < 3; ++i)
          acc += fminf(D[i * 3], fminf(D[i * 3 + 1], D[i * 3 + 2]));
      }
      out[0] = acc / 24.f;
    }
  }
}

extern "C" void kernel_launch(void* const* d_in, const int* in_sizes, int n_in,
                              void* d_out, int out_size, void* d_ws, size_t ws_size,
                              hipStream_t stream) {
  const float* src = (const float*)d_in[0];
  const float* tgt = (const float*)d_in[1];
  const float* w1 = (const float*)d_in[2];
  const float* b1 = (const float*)d_in[3];
  const float* w2 = (const float*)d_in[4];
  const float* b2 = (const float*)d_in[5];
  const float* w3 = (const float*)d_in[6];
  const float* b3 = (const float*)d_in[7];
  const float* fw1 = (const float*)d_in[8];
  const float* fb1 = (const float*)d_in[9];
  const float* fw2 = (const float*)d_in[10];
  const float* fb2 = (const float*)d_in[11];
  const float* wr = (const float*)d_in[12];
  const float* br = (const float*)d_in[13];
  const float* wt = (const float*)d_in[14];
  const float* bt = (const float*)d_in[15];
  const float* g1 = (const float*)d_in[16];
  const float* be1 = (const float*)d_in[17];
  const float* g2 = (const float*)d_in[18];
  const float* be2 = (const float*)d_in[19];
  const float* g3 = (const float*)d_in[20];
  const float* be3 = (const float*)d_in[21];
  const float* g4 = (const float*)d_in[22];
  const float* be4 = (const float*)d_in[23];
  const float* g5 = (const float*)d_in[24];
  const float* be5 = (const float*)d_in[25];
  float* out = (float*)d_out;
  float* ws = (float*)d_ws;
  u16* y2t = (u16*)(ws + WS_Y2T);
  u16* w3bf = (u16*)(ws + WS_W3BF);
  u16* w2bf = (u16*)(ws + WS_W2BF);

  k_prep<<<608, 256, 0, stream>>>(w3, w2, src, w3bf, w2bf, ws + WS_SP, ws + WS_DIST);
  k_fin1<<<1, 64, 0, stream>>>(ws + WS_SP, w1, b1, g1, be1, ws + WS_EFF1);
  k_x1stats<<<256, 256, 0, stream>>>(src, ws + WS_EFF1, ws + WS_G1P);
  k_gred1<<<20, 256, 0, stream>>>(ws + WS_G1P, ws + WS_G1);
  k_fin2<<<128, 64, 0, stream>>>(ws + WS_G1, w2, b2, g2, be2, ws + WS_SC2);
  k_conv2<<<256, 256, 0, stream>>>(src, ws + WS_EFF1, w2bf, ws + WS_SC2, y2t);
  k_conv3<<<512, 256, 0, stream>>>(y2t, w3bf, ws + WS_SUMP, ws + WS_SQP, ws + WS_MAXP);
  k_pool<<<32, 256, 0, stream>>>(ws + WS_SUMP, ws + WS_SQP, ws + WS_MAXP, b3, g3, be3,
                                 ws + WS_POOL);
  k_fc<<<512, 64, 0, stream>>>(ws + WS_POOL, fw1, fb1, g4, be4, ws + WS_FC1, 1024, 512);
  k_fc<<<256, 64, 0, stream>>>(ws + WS_FC1, fw2, fb2, g5, be5, ws + WS_FC2, 512, 256);
  k_transform<<<256, 256, 0, stream>>>(src, tgt, ws + WS_FC2, wr, br, wt, bt, out,
                                       ws + WS_DIST, (unsigned*)(ws + WS_CNT));
}